// Round 1
// 346.408 us; speedup vs baseline: 1.0132x; 1.0132x over previous
//
#include <hip/hip_runtime.h>
#include <hip/hip_bf16.h>

// GCN link-prediction: 2x GCNConv(128->128) + edge dot scoring.
// Round 13: R12 skeleton (350.9us) + {fill_csr || gemm1} fusion (independent
// work: atomic-latency-bound fill overlaps streaming GEMM) + b2 folded into
// aggregate<false> epilogue (score becomes pure dot). LESSONS BANKED:
// - aggregate gather: keep meta in registers (coalesced+shfl), 8-16 deep MLP,
//   high occupancy -> pinned at ~3.65 TB/s random-64B fabric floor.
// - never fuse latency-bound gather with reg/LDS-heavy MFMA (R10: occ collapse).
// - never read MFMA B-frags strided from global: 16B/64B line waste (R11).

#define N_NODES 100000
#define N_EDGES 1000000
#define N_LABEL 200000
#define D_FEAT 128
#define BM 128

typedef short bf16x8 __attribute__((ext_vector_type(8)));
typedef float f32x4 __attribute__((ext_vector_type(4)));

// ---- bf16 helpers (RNE) ----
__device__ inline unsigned int f2bf(float x) {
    unsigned int u = __float_as_uint(x);
    return (u + 0x7FFFu + ((u >> 16) & 1u)) >> 16;
}
__device__ inline unsigned int bf16pack(float a, float b) {
    return f2bf(a) | (f2bf(b) << 16);
}
__device__ inline float bflo(unsigned int u) { return __uint_as_float(u << 16); }
__device__ inline float bfhi(unsigned int u) { return __uint_as_float(u & 0xFFFF0000u); }

// ---------------- degree histogram + W->bf16 transpose (merged launch) ----------------
#define G_EDGE 3907  // ceil(1e6/256)
__global__ void deg_hist_w2bf(const int* __restrict__ dst, int* __restrict__ counts,
                              const float* __restrict__ W1, const float* __restrict__ W2,
                              unsigned short* __restrict__ Wt1,
                              unsigned short* __restrict__ Wt2) {
    int b = blockIdx.x;
    if (b < G_EDGE) {
        int e = b * 256 + threadIdx.x;
        if (e < N_EDGES) atomicAdd(&counts[dst[e]], 1);
    } else {
        int i = (b - G_EDGE) * 256 + threadIdx.x;  // 0..32767
        const float* W = (i < 16384) ? W1 : W2;
        unsigned short* Wt = (i < 16384) ? Wt1 : Wt2;
        int j = i & 16383;
        int n = j >> 7, k = j & 127;
        Wt[j] = (unsigned short)f2bf(W[(size_t)k * 128 + n]);
    }
}

// ---------------- scan_reduce + dinv fused ----------------
__global__ __launch_bounds__(256) void scan_reduce(const int* __restrict__ counts,
                                                   int* __restrict__ bsums,
                                                   float* __restrict__ dinv) {
    __shared__ int s[256];
    int t = threadIdx.x;
    int base = blockIdx.x * 1024 + t * 4;
    int sum = 0;
#pragma unroll
    for (int j = 0; j < 4; ++j) {
        int idx = base + j;
        if (idx < N_NODES) {
            int c = counts[idx];
            sum += c;
            dinv[idx] = rsqrtf((float)(c + 1));  // +1 self-loop
        }
    }
    s[t] = sum;
    __syncthreads();
    for (int off = 128; off > 0; off >>= 1) {
        if (t < off) s[t] += s[t + off];
        __syncthreads();
    }
    if (t == 0) bsums[blockIdx.x] = s[0];
}

// ---------------- scan_apply: block computes own bsums-prefix itself ----------------
__global__ __launch_bounds__(256) void scan_apply(const int* __restrict__ counts,
                                                  const int* __restrict__ bsums,
                                                  int* __restrict__ row_ptr) {
    __shared__ int s[256];
    int t = threadIdx.x;
    s[t] = (t < blockIdx.x) ? bsums[t] : 0;
    __syncthreads();
    for (int off = 128; off > 0; off >>= 1) {
        if (t < off) s[t] += s[t + off];
        __syncthreads();
    }
    int block_base = s[0];
    __syncthreads();

    int base = blockIdx.x * 1024 + t * 4;
    int v[4];
    int sum = 0;
#pragma unroll
    for (int j = 0; j < 4; ++j) {
        int idx = base + j;
        v[j] = (idx < N_NODES) ? counts[idx] : 0;
        sum += v[j];
    }
    s[t] = sum;
    __syncthreads();
    for (int off = 1; off < 256; off <<= 1) {
        int a = (t >= off) ? s[t - off] : 0;
        __syncthreads();
        s[t] += a;
        __syncthreads();
    }
    int excl = ((t == 0) ? 0 : s[t - 1]) + block_base;
    int run = 0;
#pragma unroll
    for (int j = 0; j < 4; ++j) {
        int idx = base + j;
        if (idx < N_NODES) row_ptr[idx] = excl + run;
        run += v[j];
    }
    if (blockIdx.x == 0 && t == 0) row_ptr[N_NODES] = N_EDGES;
}

// ---------------- MFMA GEMM body, LDS-staged bf16 W ----------------
// Block: 128 rows x 128 cols, 4 waves. Stage pre-converted Wt (bf16 [n][k],
// 32 KB) into LDS with chunk-XOR swizzle (coalesced 16B chunks); A-frags
// direct from global; fp32 accumulate; bf16 store.
template <bool BF16_IN>
__device__ __forceinline__ void gemm_body(const void* __restrict__ Xv,
                                          const unsigned short* __restrict__ Wt,
                                          unsigned int* __restrict__ Y,
                                          int nrows, int bid, short* Ws) {
    int t = threadIdx.x;

    // stage: 2048 16B chunks, coalesced global reads, swizzled LDS stores
#pragma unroll
    for (int i = 0; i < 8; ++i) {
        int c = i * 256 + t;
        int n = c >> 4, q = c & 15;
        uint4 v = *(const uint4*)&Wt[(size_t)n * 128 + q * 8];
        *(uint4*)&Ws[n * 128 + ((q ^ (n & 15)) << 3)] = v;
    }
    __syncthreads();

    int wv = t >> 6;
    int lane = t & 63, l16 = lane & 15, quad = lane >> 4;
    int rbase = bid * BM + wv * 32;

    f32x4 acc[2][8];
#pragma unroll
    for (int rt = 0; rt < 2; ++rt)
#pragma unroll
        for (int nt = 0; nt < 8; ++nt) acc[rt][nt] = (f32x4){0.f, 0.f, 0.f, 0.f};

#pragma unroll
    for (int kb = 0; kb < 4; ++kb) {
        bf16x8 af[2];
#pragma unroll
        for (int rt = 0; rt < 2; ++rt) {
            int row = rbase + rt * 16 + l16;
            if (row > nrows - 1) row = nrows - 1;
            if constexpr (BF16_IN) {
                const unsigned int* Xb = (const unsigned int*)Xv;
                af[rt] = *(const bf16x8*)&Xb[(size_t)row * 64 + kb * 16 + quad * 4];
            } else {
                const float* X = (const float*)Xv;
                float4 fa = ((const float4*)X)[(size_t)row * 32 + kb * 8 + quad * 2];
                float4 fb = ((const float4*)X)[(size_t)row * 32 + kb * 8 + quad * 2 + 1];
                union { uint4 u; bf16x8 v; } cv;
                cv.u.x = bf16pack(fa.x, fa.y);
                cv.u.y = bf16pack(fa.z, fa.w);
                cv.u.z = bf16pack(fb.x, fb.y);
                cv.u.w = bf16pack(fb.z, fb.w);
                af[rt] = cv.v;
            }
        }
        bf16x8 bfr[8];
#pragma unroll
        for (int nt = 0; nt < 8; ++nt) {
            int n = nt * 16 + l16;
            bfr[nt] = *(const bf16x8*)&Ws[n * 128 + (((kb * 4 + quad) ^ l16) << 3)];
        }
#pragma unroll
        for (int rt = 0; rt < 2; ++rt)
#pragma unroll
            for (int nt = 0; nt < 8; ++nt)
                acc[rt][nt] = __builtin_amdgcn_mfma_f32_16x16x32_bf16(
                    af[rt], bfr[nt], acc[rt][nt], 0, 0, 0);
    }

    short* Ys = (short*)Y;
#pragma unroll
    for (int rt = 0; rt < 2; ++rt)
#pragma unroll
        for (int reg = 0; reg < 4; ++reg) {
            int row = rbase + rt * 16 + quad * 4 + reg;
            if (row < nrows) {
#pragma unroll
                for (int nt = 0; nt < 8; ++nt)
                    Ys[(size_t)row * 128 + nt * 16 + l16] = (short)f2bf(acc[rt][nt][reg]);
            }
        }
}

// standalone GEMM (layer 2, bf16 input)
__global__ __launch_bounds__(256) void gemm128_mfma_bf16(const unsigned int* __restrict__ Xb,
                                                         const unsigned short* __restrict__ Wt,
                                                         unsigned int* __restrict__ Y,
                                                         int nrows) {
    __shared__ short Ws[128 * 128];
    gemm_body<true>(Xb, Wt, Y, nrows, blockIdx.x, Ws);
}

// ---------------- fused: gemm1 (f32 input) || fill_csr ----------------
// fill_csr is atomic/latency-bound (1M atomicSub + random 8B scatter, low BW);
// gemm1 is streaming-BW. Independent -> pack into one launch. LDS (32 KB)
// caps fill blocks at 5/CU, so fill runs 4 edges/thread for 4x MLP.
#define G_GEMM 782   // ceil(100000/128)
#define G_FILL 977   // ceil(1e6/1024)
__global__ __launch_bounds__(256) void fused_fill_gemm(
    const int* __restrict__ src, const int* __restrict__ dst,
    const float* __restrict__ dinv, const int* __restrict__ row_ptr,
    int* __restrict__ counts, int2* __restrict__ packed,
    const float* __restrict__ feat, const unsigned short* __restrict__ wt1,
    unsigned int* __restrict__ Hb) {
    __shared__ short Ws[128 * 128];  // used by gemm blocks only
    int b = blockIdx.x;
    if (b < G_GEMM) {
        gemm_body<false>(feat, wt1, Hb, N_NODES, b, Ws);
        return;
    }
    int bb = b - G_GEMM;
    int t0 = bb * 1024 + threadIdx.x;
#pragma unroll
    for (int j = 0; j < 4; ++j) {
        int e = t0 + j * 256;
        if (e < N_EDGES) {
            int s = src[e], d = dst[e];
            int pos = row_ptr[d] + atomicSub(&counts[d], 1) - 1;
            float norm = dinv[s] * dinv[d];
            packed[pos] = make_int2(s, __float_as_int(norm));
        }
    }
}

// ---------------- gather-aggregate: 2 nodes/wave, 16 gathers in flight ----
// bias is ALWAYS added (b2 folded here for layer 2; score is then a pure dot).
template <bool RELU>
__global__ __launch_bounds__(256) void aggregate(const unsigned int* __restrict__ Hb,
                                                 const int2* __restrict__ packed,
                                                 const int* __restrict__ row_ptr,
                                                 const float* __restrict__ dinv,
                                                 const float* __restrict__ bias,
                                                 unsigned int* __restrict__ Xb) {
    int v0 = blockIdx.x * 8 + (threadIdx.x >> 6) * 2;
    int v1 = v0 + 1;
    int lane = threadIdx.x & 63;
    if (v0 >= N_NODES) return;
    bool h1 = (v1 < N_NODES);

    int st0 = row_ptr[v0], en0 = row_ptr[v0 + 1];
    int st1 = h1 ? row_ptr[v1] : 0, en1 = h1 ? row_ptr[v1 + 1] : 0;
    float dv0 = dinv[v0], d20 = dv0 * dv0;
    float dv1 = h1 ? dinv[v1] : 0.f, d21 = dv1 * dv1;

    unsigned int su0 = Hb[(size_t)v0 * 64 + lane];
    float a0 = d20 * bflo(su0), a1 = d20 * bfhi(su0);
    unsigned int su1 = h1 ? Hb[(size_t)v1 * 64 + lane] : 0u;
    float b0 = d21 * bflo(su1), b1 = d21 * bfhi(su1);

    for (int c0 = st0, c1 = st1; c0 < en0 || c1 < en1; c0 += 32, c1 += 32) {
        int n0 = en0 - c0; n0 = n0 < 0 ? 0 : (n0 > 32 ? 32 : n0);
        int n1 = en1 - c1; n1 = n1 < 0 ? 0 : (n1 > 32 ? 32 : n1);
        int2 p = make_int2(0, 0);
        if (lane < 32) {
            if (lane < n0) p = packed[c0 + lane];
        } else {
            if (lane - 32 < n1) p = packed[c1 + lane - 32];
        }
        int nmax = n0 > n1 ? n0 : n1;
        for (int j = 0; j < nmax; j += 8) {
            int sA[8], sB[8];
            float nrA[8], nrB[8];
#pragma unroll
            for (int q = 0; q < 8; ++q) {
                sA[q] = __shfl(p.x, j + q);
                nrA[q] = __int_as_float(__shfl(p.y, j + q));
                sB[q] = __shfl(p.x, 32 + j + q);
                nrB[q] = __int_as_float(__shfl(p.y, 32 + j + q));
            }
            unsigned int uA[8], uB[8];
#pragma unroll
            for (int q = 0; q < 8; ++q) {
                uA[q] = Hb[(size_t)sA[q] * 64 + lane];
                uB[q] = Hb[(size_t)sB[q] * 64 + lane];
            }
#pragma unroll
            for (int q = 0; q < 8; ++q) {
                a0 = fmaf(nrA[q], bflo(uA[q]), a0);
                a1 = fmaf(nrA[q], bfhi(uA[q]), a1);
                b0 = fmaf(nrB[q], bflo(uB[q]), b0);
                b1 = fmaf(nrB[q], bfhi(uB[q]), b1);
            }
        }
    }

    float2 bb = ((const float2*)bias)[lane];
    a0 += bb.x; a1 += bb.y;
    b0 += bb.x; b1 += bb.y;
    if (RELU) {
        a0 = fmaxf(a0, 0.f);
        a1 = fmaxf(a1, 0.f);
        b0 = fmaxf(b0, 0.f);
        b1 = fmaxf(b1, 0.f);
    }
    Xb[(size_t)v0 * 64 + lane] = bf16pack(a0, a1);
    if (h1) Xb[(size_t)v1 * 64 + lane] = bf16pack(b0, b1);
}

// ---------------- edge scoring: 4 label edges per wave (bias pre-folded) ----
__global__ __launch_bounds__(256) void score_kernel(const int* __restrict__ ea,
                                                    const int* __restrict__ eb,
                                                    const unsigned int* __restrict__ Xb,
                                                    float* __restrict__ out) {
    int wbase = (blockIdx.x * 4 + (threadIdx.x >> 6)) * 4;
    int lane = threadIdx.x & 63;
    if (wbase >= N_LABEL) return;
    int ne = N_LABEL - wbase;
    if (ne > 4) ne = 4;

    unsigned int ua[4], ub[4];
#pragma unroll
    for (int e = 0; e < 4; ++e)
        if (e < ne) {
            int ia = ea[wbase + e], ib = eb[wbase + e];
            ua[e] = Xb[(size_t)ia * 64 + lane];
            ub[e] = Xb[(size_t)ib * 64 + lane];
        }
#pragma unroll
    for (int e = 0; e < 4; ++e)
        if (e < ne) {
            float p = bflo(ua[e]) * bflo(ub[e]) + bfhi(ua[e]) * bfhi(ub[e]);
#pragma unroll
            for (int off = 32; off > 0; off >>= 1) p += __shfl_down(p, off);
            if (lane == 0) out[wbase + e] = p;
        }
}

extern "C" void kernel_launch(void* const* d_in, const int* in_sizes, int n_in,
                              void* d_out, int out_size, void* d_ws, size_t ws_size,
                              hipStream_t stream) {
    const float* feat = (const float*)d_in[0];
    const int* ei = (const int*)d_in[1];
    const int* eli = (const int*)d_in[2];
    const float* W1 = (const float*)d_in[3];
    const float* b1 = (const float*)d_in[4];
    const float* W2 = (const float*)d_in[5];
    const float* b2 = (const float*)d_in[6];
    float* out = (float*)d_out;

    const int* src = ei;
    const int* dst = ei + N_EDGES;
    const int* la = eli;
    const int* lb = eli + N_LABEL;

    int* counts = (int*)d_ws;                        // N ints
    int* row_ptr = counts + N_NODES;                 // N+4 ints
    int* bsums = row_ptr + N_NODES + 4;              // 128
    float* dinv = (float*)(bsums + 128);             // N
    unsigned short* wt1 = (unsigned short*)(dinv + N_NODES);  // 16384 ushort
    unsigned short* wt2 = wt1 + 16384;                        // 16384 ushort
    int2* packed = (int2*)(wt2 + 16384);                      // E int2 (8 MB)
    unsigned int* Hb = (unsigned int*)(packed + N_EDGES);     // N*64 uints
    unsigned int* Xb = Hb + (size_t)N_NODES * 64;             // N*64 uints

    const int TB = 256;
    int gScan = (N_NODES + 1023) / 1024;     // 98
    int gGemm = (N_NODES + BM - 1) / BM;     // 782
    int gAgg = (N_NODES + 7) / 8;            // 12500
    int gScore = (N_LABEL + 15) / 16;        // 12500

    hipMemsetAsync(counts, 0, N_NODES * sizeof(int), stream);

    // CSR build front-end (+ W conversion folded into first launch)
    deg_hist_w2bf<<<G_EDGE + 128, TB, 0, stream>>>(dst, counts, W1, W2, wt1, wt2);
    scan_reduce<<<gScan, TB, 0, stream>>>(counts, bsums, dinv);
    scan_apply<<<gScan, TB, 0, stream>>>(counts, bsums, row_ptr);

    // fill_csr || gemm1 (independent; latency-bound atomics overlap streaming GEMM)
    fused_fill_gemm<<<G_GEMM + G_FILL, TB, 0, stream>>>(src, dst, dinv, row_ptr,
                                                        counts, packed, feat, wt1, Hb);

    // layer 1 aggregate
    aggregate<true><<<gAgg, TB, 0, stream>>>(Hb, packed, row_ptr, dinv, b1, Xb);

    // layer 2
    gemm128_mfma_bf16<<<gGemm, TB, 0, stream>>>(Xb, wt2, Hb, N_NODES);
    aggregate<false><<<gAgg, TB, 0, stream>>>(Hb, packed, row_ptr, dinv, b2, Xb);

    // scoring (b2 already folded into Xb)
    score_kernel<<<gScore, TB, 0, stream>>>(la, lb, Xb, out);
}

// Round 2
// 289.171 us; speedup vs baseline: 1.2137x; 1.1979x over previous
//
#include <hip/hip_runtime.h>
#include <hip/hip_bf16.h>

// GCN link-prediction: 2x GCNConv(128->128) + edge dot scoring.
// Round 14: replace atomic CSR build (deg_hist 1M fabric atomics + fill_csr
// 1M random 8B scatters, ~110us combined, WRITE_SIZE showed 8x write-allocate
// thrash) with 2-pass LDS counting sort:
//   pass1: coarse bucket by dst>>7, LDS hist+rank, 1 global atomic per
//          (block,bucket), packed 24-bit records, contiguous-run scatter.
//   pass2: per-bucket LDS fine sort (all fine atomics in LDS), contiguous
//          full-line packed/row_ptr/dinv writes.
//   pass3: norm fixup (packed.y *= dinv[src]) fused into gemm1 launch.
// LESSONS BANKED:
// - aggregate gather: pinned at ~3.65 TB/s random-64B fabric floor.
// - never fuse latency-bound gather with reg/LDS-heavy MFMA (R10).
// - never read MFMA B-frags strided from global (R11).
// - random 8B scatter = 8x write amplification (R13 WRITE_SIZE 92MB vs 34MB);
//   atomics+scatter are fabric-THROUGHPUT-bound, overlap doesn't help.

#define N_NODES 100000
#define N_EDGES 1000000
#define N_LABEL 200000
#define D_FEAT 128
#define BM 128

#define NB 782        // coarse buckets: ceil(100000/128) nodes each
#define BCAP 2048     // temp capacity per bucket (mean 1279, +6sigma ~1500)
#define P1_EPT 16     // pass1 edges per thread
#define P1_BLOCKS 245 // ceil(1e6/4096)

typedef short bf16x8 __attribute__((ext_vector_type(8)));
typedef float f32x4 __attribute__((ext_vector_type(4)));

// ---- bf16 helpers (RNE) ----
__device__ inline unsigned int f2bf(float x) {
    unsigned int u = __float_as_uint(x);
    return (u + 0x7FFFu + ((u >> 16) & 1u)) >> 16;
}
__device__ inline unsigned int bf16pack(float a, float b) {
    return f2bf(a) | (f2bf(b) << 16);
}
__device__ inline float bflo(unsigned int u) { return __uint_as_float(u << 16); }
__device__ inline float bfhi(unsigned int u) { return __uint_as_float(u & 0xFFFF0000u); }

// ---------------- pass 1: coarse bucket by dst>>7 (+ W->bf16 merged) --------
// Per block: 4096 edges. LDS hist over 782 buckets gives per-edge rank;
// one global atomicAdd per (block,bucket) reserves the run; scatter packed
// 24-bit records ((dst&127)<<17 | src) in ~5-edge contiguous runs.
__global__ __launch_bounds__(256) void pass1_bucket_w2bf(
    const int* __restrict__ src, const int* __restrict__ dst,
    int* __restrict__ gcur, unsigned int* __restrict__ temp,
    const float* __restrict__ W1, const float* __restrict__ W2,
    unsigned short* __restrict__ Wt1, unsigned short* __restrict__ Wt2) {
    int b = blockIdx.x, t = threadIdx.x;
    if (b >= P1_BLOCKS) {
        int i = (b - P1_BLOCKS) * 256 + t;  // 0..32767
        const float* W = (i < 16384) ? W1 : W2;
        unsigned short* Wt = (i < 16384) ? Wt1 : Wt2;
        int j = i & 16383;
        int n = j >> 7, k = j & 127;
        Wt[j] = (unsigned short)f2bf(W[(size_t)k * 128 + n]);
        return;
    }
    __shared__ int hist[NB], base[NB];
    for (int i = t; i < NB; i += 256) hist[i] = 0;
    __syncthreads();

    int se[P1_EPT], de[P1_EPT], rk[P1_EPT];
    int e0 = b * (P1_EPT * 256) + t;
#pragma unroll
    for (int j = 0; j < P1_EPT; ++j) {
        int e = e0 + j * 256;
        if (e < N_EDGES) {
            se[j] = src[e];
            de[j] = dst[e];
            rk[j] = atomicAdd(&hist[de[j] >> 7], 1);
        }
    }
    __syncthreads();
    for (int i = t; i < NB; i += 256) {
        int h = hist[i];
        base[i] = h ? atomicAdd(&gcur[i], h) : 0;
    }
    __syncthreads();
#pragma unroll
    for (int j = 0; j < P1_EPT; ++j) {
        int e = e0 + j * 256;
        if (e < N_EDGES) {
            int k = de[j] >> 7;
            int pos = base[k] + rk[j];
            if (pos < BCAP)
                temp[(size_t)k * BCAP + pos] =
                    (unsigned int)(((de[j] & 127) << 17) | se[j]);
        }
    }
}

// ---------------- pass 2: per-bucket LDS fine counting sort ------------------
// Block k sorts bucket k (nodes [k*128,(k+1)*128)): LDS hist (128 bins, LDS
// atomics), LDS scan -> row_ptr/dinv for its nodes, scatter packed
// (src, dinv_dst) into its contiguous output region.
__global__ __launch_bounds__(256) void pass2_sort(
    const int* __restrict__ gcur, const unsigned int* __restrict__ temp,
    int* __restrict__ row_ptr, float* __restrict__ dinv,
    int2* __restrict__ packed) {
    int k = blockIdx.x, t = threadIdx.x;
    __shared__ unsigned int ed[BCAP];
    __shared__ int hist[128], rp[128], cur[128], sc[128];
    __shared__ float dvl[128];
    __shared__ int red[256];

    // gbase = sum of gcur[j] for j<k (gcur is tiny and L2-hot)
    int part = 0;
    for (int j = t; j < NB; j += 256)
        if (j < k) part += gcur[j];
    red[t] = part;
    __syncthreads();
    for (int off = 128; off > 0; off >>= 1) {
        if (t < off) red[t] += red[t + off];
        __syncthreads();
    }
    int gbase = red[0];
    int nk = gcur[k];
    if (nk > BCAP) nk = BCAP;

    if (t < 128) { hist[t] = 0; cur[t] = 0; }
    __syncthreads();
    for (int i = t; i < nk; i += 256) {
        unsigned int v = temp[(size_t)k * BCAP + i];
        ed[i] = v;
        atomicAdd(&hist[v >> 17], 1);
    }
    __syncthreads();

    // exclusive scan over 128 bins
    if (t < 128) sc[t] = hist[t];
    __syncthreads();
    for (int off = 1; off < 128; off <<= 1) {
        int a = (t < 128 && t >= off) ? sc[t - off] : 0;
        __syncthreads();
        if (t < 128) sc[t] += a;
        __syncthreads();
    }
    if (t < 128) {
        rp[t] = sc[t] - hist[t];
        float dv = rsqrtf((float)(hist[t] + 1));  // +1 self-loop
        dvl[t] = dv;
        int n = k * 128 + t;
        if (n < N_NODES) {
            row_ptr[n] = gbase + rp[t];
            dinv[n] = dv;
        }
    }
    if (k == NB - 1 && t == 0) row_ptr[N_NODES] = N_EDGES;
    __syncthreads();

    for (int i = t; i < nk; i += 256) {
        unsigned int v = ed[i];
        int dl = v >> 17;
        int r = atomicAdd(&cur[dl], 1);
        packed[gbase + rp[dl] + r] =
            make_int2((int)(v & 0x1FFFF), __float_as_int(dvl[dl]));
    }
}

// ---------------- MFMA GEMM body, LDS-staged bf16 W ----------------
template <bool BF16_IN>
__device__ __forceinline__ void gemm_body(const void* __restrict__ Xv,
                                          const unsigned short* __restrict__ Wt,
                                          unsigned int* __restrict__ Y,
                                          int nrows, int bid, short* Ws) {
    int t = threadIdx.x;
#pragma unroll
    for (int i = 0; i < 8; ++i) {
        int c = i * 256 + t;
        int n = c >> 4, q = c & 15;
        uint4 v = *(const uint4*)&Wt[(size_t)n * 128 + q * 8];
        *(uint4*)&Ws[n * 128 + ((q ^ (n & 15)) << 3)] = v;
    }
    __syncthreads();

    int wv = t >> 6;
    int lane = t & 63, l16 = lane & 15, quad = lane >> 4;
    int rbase = bid * BM + wv * 32;

    f32x4 acc[2][8];
#pragma unroll
    for (int rt = 0; rt < 2; ++rt)
#pragma unroll
        for (int nt = 0; nt < 8; ++nt) acc[rt][nt] = (f32x4){0.f, 0.f, 0.f, 0.f};

#pragma unroll
    for (int kb = 0; kb < 4; ++kb) {
        bf16x8 af[2];
#pragma unroll
        for (int rt = 0; rt < 2; ++rt) {
            int row = rbase + rt * 16 + l16;
            if (row > nrows - 1) row = nrows - 1;
            if constexpr (BF16_IN) {
                const unsigned int* Xb = (const unsigned int*)Xv;
                af[rt] = *(const bf16x8*)&Xb[(size_t)row * 64 + kb * 16 + quad * 4];
            } else {
                const float* X = (const float*)Xv;
                float4 fa = ((const float4*)X)[(size_t)row * 32 + kb * 8 + quad * 2];
                float4 fb = ((const float4*)X)[(size_t)row * 32 + kb * 8 + quad * 2 + 1];
                union { uint4 u; bf16x8 v; } cv;
                cv.u.x = bf16pack(fa.x, fa.y);
                cv.u.y = bf16pack(fa.z, fa.w);
                cv.u.z = bf16pack(fb.x, fb.y);
                cv.u.w = bf16pack(fb.z, fb.w);
                af[rt] = cv.v;
            }
        }
        bf16x8 bfr[8];
#pragma unroll
        for (int nt = 0; nt < 8; ++nt) {
            int n = nt * 16 + l16;
            bfr[nt] = *(const bf16x8*)&Ws[n * 128 + (((kb * 4 + quad) ^ l16) << 3)];
        }
#pragma unroll
        for (int rt = 0; rt < 2; ++rt)
#pragma unroll
            for (int nt = 0; nt < 8; ++nt)
                acc[rt][nt] = __builtin_amdgcn_mfma_f32_16x16x32_bf16(
                    af[rt], bfr[nt], acc[rt][nt], 0, 0, 0);
    }

    short* Ys = (short*)Y;
#pragma unroll
    for (int rt = 0; rt < 2; ++rt)
#pragma unroll
        for (int reg = 0; reg < 4; ++reg) {
            int row = rbase + rt * 16 + quad * 4 + reg;
            if (row < nrows) {
#pragma unroll
                for (int nt = 0; nt < 8; ++nt)
                    Ys[(size_t)row * 128 + nt * 16 + l16] = (short)f2bf(acc[rt][nt][reg]);
            }
        }
}

// standalone GEMM (layer 2, bf16 input)
__global__ __launch_bounds__(256) void gemm128_mfma_bf16(const unsigned int* __restrict__ Xb,
                                                         const unsigned short* __restrict__ Wt,
                                                         unsigned int* __restrict__ Y,
                                                         int nrows) {
    __shared__ short Ws[128 * 128];
    gemm_body<true>(Xb, Wt, Y, nrows, blockIdx.x, Ws);
}

// ---------------- fused: gemm1 (f32 input) || norm fixup ----------------
// norm fixup: packed.y = dinv_dst * dinv[src] (streaming RMW + hot gather);
// independent of gemm1, overlaps under it.
#define G_GEMM 782  // ceil(100000/128)
#define G_FIX 977   // ceil(1e6/1024)
__global__ __launch_bounds__(256) void fused_norm_gemm(
    const float* __restrict__ feat, const unsigned short* __restrict__ wt1,
    unsigned int* __restrict__ Hb, int2* __restrict__ packed,
    const float* __restrict__ dinv) {
    __shared__ short Ws[128 * 128];  // used by gemm blocks only
    int b = blockIdx.x;
    if (b < G_GEMM) {
        gemm_body<false>(feat, wt1, Hb, N_NODES, b, Ws);
        return;
    }
    int bb = b - G_GEMM;
    int t0 = bb * 1024 + threadIdx.x;
#pragma unroll
    for (int j = 0; j < 4; ++j) {
        int e = t0 + j * 256;
        if (e < N_EDGES) {
            int2 p = packed[e];
            p.y = __float_as_int(__int_as_float(p.y) * dinv[p.x]);
            packed[e] = p;
        }
    }
}

// ---------------- gather-aggregate: 2 nodes/wave, 16 gathers in flight ----
// bias is ALWAYS added (b2 folded here for layer 2; score is then a pure dot).
template <bool RELU>
__global__ __launch_bounds__(256) void aggregate(const unsigned int* __restrict__ Hb,
                                                 const int2* __restrict__ packed,
                                                 const int* __restrict__ row_ptr,
                                                 const float* __restrict__ dinv,
                                                 const float* __restrict__ bias,
                                                 unsigned int* __restrict__ Xb) {
    int v0 = blockIdx.x * 8 + (threadIdx.x >> 6) * 2;
    int v1 = v0 + 1;
    int lane = threadIdx.x & 63;
    if (v0 >= N_NODES) return;
    bool h1 = (v1 < N_NODES);

    int st0 = row_ptr[v0], en0 = row_ptr[v0 + 1];
    int st1 = h1 ? row_ptr[v1] : 0, en1 = h1 ? row_ptr[v1 + 1] : 0;
    float dv0 = dinv[v0], d20 = dv0 * dv0;
    float dv1 = h1 ? dinv[v1] : 0.f, d21 = dv1 * dv1;

    unsigned int su0 = Hb[(size_t)v0 * 64 + lane];
    float a0 = d20 * bflo(su0), a1 = d20 * bfhi(su0);
    unsigned int su1 = h1 ? Hb[(size_t)v1 * 64 + lane] : 0u;
    float b0 = d21 * bflo(su1), b1 = d21 * bfhi(su1);

    for (int c0 = st0, c1 = st1; c0 < en0 || c1 < en1; c0 += 32, c1 += 32) {
        int n0 = en0 - c0; n0 = n0 < 0 ? 0 : (n0 > 32 ? 32 : n0);
        int n1 = en1 - c1; n1 = n1 < 0 ? 0 : (n1 > 32 ? 32 : n1);
        int2 p = make_int2(0, 0);
        if (lane < 32) {
            if (lane < n0) p = packed[c0 + lane];
        } else {
            if (lane - 32 < n1) p = packed[c1 + lane - 32];
        }
        int nmax = n0 > n1 ? n0 : n1;
        for (int j = 0; j < nmax; j += 8) {
            int sA[8], sB[8];
            float nrA[8], nrB[8];
#pragma unroll
            for (int q = 0; q < 8; ++q) {
                sA[q] = __shfl(p.x, j + q);
                nrA[q] = __int_as_float(__shfl(p.y, j + q));
                sB[q] = __shfl(p.x, 32 + j + q);
                nrB[q] = __int_as_float(__shfl(p.y, 32 + j + q));
            }
            unsigned int uA[8], uB[8];
#pragma unroll
            for (int q = 0; q < 8; ++q) {
                uA[q] = Hb[(size_t)sA[q] * 64 + lane];
                uB[q] = Hb[(size_t)sB[q] * 64 + lane];
            }
#pragma unroll
            for (int q = 0; q < 8; ++q) {
                a0 = fmaf(nrA[q], bflo(uA[q]), a0);
                a1 = fmaf(nrA[q], bfhi(uA[q]), a1);
                b0 = fmaf(nrB[q], bflo(uB[q]), b0);
                b1 = fmaf(nrB[q], bfhi(uB[q]), b1);
            }
        }
    }

    float2 bb = ((const float2*)bias)[lane];
    a0 += bb.x; a1 += bb.y;
    b0 += bb.x; b1 += bb.y;
    if (RELU) {
        a0 = fmaxf(a0, 0.f);
        a1 = fmaxf(a1, 0.f);
        b0 = fmaxf(b0, 0.f);
        b1 = fmaxf(b1, 0.f);
    }
    Xb[(size_t)v0 * 64 + lane] = bf16pack(a0, a1);
    if (h1) Xb[(size_t)v1 * 64 + lane] = bf16pack(b0, b1);
}

// ---------------- edge scoring: 4 label edges per wave (bias pre-folded) ----
__global__ __launch_bounds__(256) void score_kernel(const int* __restrict__ ea,
                                                    const int* __restrict__ eb,
                                                    const unsigned int* __restrict__ Xb,
                                                    float* __restrict__ out) {
    int wbase = (blockIdx.x * 4 + (threadIdx.x >> 6)) * 4;
    int lane = threadIdx.x & 63;
    if (wbase >= N_LABEL) return;
    int ne = N_LABEL - wbase;
    if (ne > 4) ne = 4;

    unsigned int ua[4], ub[4];
#pragma unroll
    for (int e = 0; e < 4; ++e)
        if (e < ne) {
            int ia = ea[wbase + e], ib = eb[wbase + e];
            ua[e] = Xb[(size_t)ia * 64 + lane];
            ub[e] = Xb[(size_t)ib * 64 + lane];
        }
#pragma unroll
    for (int e = 0; e < 4; ++e)
        if (e < ne) {
            float p = bflo(ua[e]) * bflo(ub[e]) + bfhi(ua[e]) * bfhi(ub[e]);
#pragma unroll
            for (int off = 32; off > 0; off >>= 1) p += __shfl_down(p, off);
            if (lane == 0) out[wbase + e] = p;
        }
}

extern "C" void kernel_launch(void* const* d_in, const int* in_sizes, int n_in,
                              void* d_out, int out_size, void* d_ws, size_t ws_size,
                              hipStream_t stream) {
    const float* feat = (const float*)d_in[0];
    const int* ei = (const int*)d_in[1];
    const int* eli = (const int*)d_in[2];
    const float* W1 = (const float*)d_in[3];
    const float* b1 = (const float*)d_in[4];
    const float* W2 = (const float*)d_in[5];
    const float* b2 = (const float*)d_in[6];
    float* out = (float*)d_out;

    const int* src = ei;
    const int* dst = ei + N_EDGES;
    const int* la = eli;
    const int* lb = eli + N_LABEL;

    int* gcur = (int*)d_ws;                                   // NB (pad 1024)
    int* row_ptr = gcur + 1024;                               // N+4 ints
    float* dinv = (float*)(row_ptr + N_NODES + 4);            // N
    unsigned short* wt1 = (unsigned short*)(dinv + N_NODES);  // 16384 ushort
    unsigned short* wt2 = wt1 + 16384;                        // 16384 ushort
    int2* packed = (int2*)(wt2 + 16384);                      // E int2 (8 MB)
    unsigned int* Hb = (unsigned int*)(packed + N_EDGES);     // N*64 uints
    unsigned int* Xb = Hb + (size_t)N_NODES * 64;             // N*64 uints
    unsigned int* temp = Xb;  // pass1/2 temp (6.4 MB) aliases Xb (dead til agg1)

    const int TB = 256;
    int gGemm = (N_NODES + BM - 1) / BM;  // 782
    int gAgg = (N_NODES + 7) / 8;         // 12500
    int gScore = (N_LABEL + 15) / 16;     // 12500

    hipMemsetAsync(gcur, 0, NB * sizeof(int), stream);

    // CSR build: 2-pass LDS counting sort (+ W conversion folded into pass 1)
    pass1_bucket_w2bf<<<P1_BLOCKS + 128, TB, 0, stream>>>(src, dst, gcur, temp,
                                                          W1, W2, wt1, wt2);
    pass2_sort<<<NB, TB, 0, stream>>>(gcur, temp, row_ptr, dinv, packed);

    // norm fixup || gemm1 (independent; streaming fixup hides under GEMM)
    fused_norm_gemm<<<G_GEMM + G_FIX, TB, 0, stream>>>(feat, wt1, Hb, packed, dinv);

    // layer 1 aggregate
    aggregate<true><<<gAgg, TB, 0, stream>>>(Hb, packed, row_ptr, dinv, b1, Xb);

    // layer 2
    gemm128_mfma_bf16<<<gGemm, TB, 0, stream>>>(Xb, wt2, Hb, N_NODES);
    aggregate<false><<<gAgg, TB, 0, stream>>>(Hb, packed, row_ptr, dinv, b2, Xb);

    // scoring (b2 already folded into Xb)
    score_kernel<<<gScore, TB, 0, stream>>>(la, lb, Xb, out);
}

// Round 3
// 282.390 us; speedup vs baseline: 1.2429x; 1.0240x over previous
//
#include <hip/hip_runtime.h>
#include <hip/hip_bf16.h>

// GCN link-prediction: 2x GCNConv(128->128) + edge dot scoring.
// Round 15: norm factorization. norm = dinv[dst]*dinv[src] and dinv[dst] is
// UNIFORM within a node's CSR segment -> x[v] = dv*(sum_s dinv[s]*H[s] + dv*H[v]).
// So: packed shrinks int2->int (8->4 MB), the norm-fixup pass is deleted,
// aggregate meta-lanes gather dinv[src] from the L2-hot 400KB array, and
// pass2 (no longer feeding a fixup) fuses with gemm1 in one launch.
// LESSONS BANKED:
// - aggregate gather: pinned at ~3.65 TB/s random-64B fabric floor.
// - never fuse latency-bound gather with reg/LDS-heavy MFMA (R10).
// - never read MFMA B-frags strided from global (R11).
// - random 8B scatter = 8x write amplification; atomics+scatter are
//   fabric-THROUGHPUT-bound, overlap doesn't help (R13).
// - CSR via 2-pass LDS counting sort >> 1M global atomics (R14: -57us).

#define N_NODES 100000
#define N_EDGES 1000000
#define N_LABEL 200000
#define D_FEAT 128
#define BM 128

#define NB 782        // coarse buckets: ceil(100000/128) nodes each
#define BCAP 2048     // temp capacity per bucket (mean 1279, +6sigma ~1500)
#define P1_EPT 16     // pass1 edges per thread
#define P1_BLOCKS 245 // ceil(1e6/4096)

typedef short bf16x8 __attribute__((ext_vector_type(8)));
typedef float f32x4 __attribute__((ext_vector_type(4)));

// ---- bf16 helpers (RNE) ----
__device__ inline unsigned int f2bf(float x) {
    unsigned int u = __float_as_uint(x);
    return (u + 0x7FFFu + ((u >> 16) & 1u)) >> 16;
}
__device__ inline unsigned int bf16pack(float a, float b) {
    return f2bf(a) | (f2bf(b) << 16);
}
__device__ inline float bflo(unsigned int u) { return __uint_as_float(u << 16); }
__device__ inline float bfhi(unsigned int u) { return __uint_as_float(u & 0xFFFF0000u); }

// ---------------- pass 1: coarse bucket by dst>>7 (+ W->bf16 merged) --------
__global__ __launch_bounds__(256) void pass1_bucket_w2bf(
    const int* __restrict__ src, const int* __restrict__ dst,
    int* __restrict__ gcur, unsigned int* __restrict__ temp,
    const float* __restrict__ W1, const float* __restrict__ W2,
    unsigned short* __restrict__ Wt1, unsigned short* __restrict__ Wt2) {
    int b = blockIdx.x, t = threadIdx.x;
    if (b >= P1_BLOCKS) {
        int i = (b - P1_BLOCKS) * 256 + t;  // 0..32767
        const float* W = (i < 16384) ? W1 : W2;
        unsigned short* Wt = (i < 16384) ? Wt1 : Wt2;
        int j = i & 16383;
        int n = j >> 7, k = j & 127;
        Wt[j] = (unsigned short)f2bf(W[(size_t)k * 128 + n]);
        return;
    }
    __shared__ int hist[NB], base[NB];
    for (int i = t; i < NB; i += 256) hist[i] = 0;
    __syncthreads();

    int se[P1_EPT], de[P1_EPT], rk[P1_EPT];
    int e0 = b * (P1_EPT * 256) + t;
#pragma unroll
    for (int j = 0; j < P1_EPT; ++j) {
        int e = e0 + j * 256;
        if (e < N_EDGES) {
            se[j] = src[e];
            de[j] = dst[e];
            rk[j] = atomicAdd(&hist[de[j] >> 7], 1);
        }
    }
    __syncthreads();
    for (int i = t; i < NB; i += 256) {
        int h = hist[i];
        base[i] = h ? atomicAdd(&gcur[i], h) : 0;
    }
    __syncthreads();
#pragma unroll
    for (int j = 0; j < P1_EPT; ++j) {
        int e = e0 + j * 256;
        if (e < N_EDGES) {
            int k = de[j] >> 7;
            int pos = base[k] + rk[j];
            if (pos < BCAP)
                temp[(size_t)k * BCAP + pos] =
                    (unsigned int)(((de[j] & 127) << 17) | se[j]);
        }
    }
}

// ---------------- MFMA GEMM body, LDS-staged bf16 W ----------------
template <bool BF16_IN>
__device__ __forceinline__ void gemm_body(const void* __restrict__ Xv,
                                          const unsigned short* __restrict__ Wt,
                                          unsigned int* __restrict__ Y,
                                          int nrows, int bid, short* Ws) {
    int t = threadIdx.x;
#pragma unroll
    for (int i = 0; i < 8; ++i) {
        int c = i * 256 + t;
        int n = c >> 4, q = c & 15;
        uint4 v = *(const uint4*)&Wt[(size_t)n * 128 + q * 8];
        *(uint4*)&Ws[n * 128 + ((q ^ (n & 15)) << 3)] = v;
    }
    __syncthreads();

    int wv = t >> 6;
    int lane = t & 63, l16 = lane & 15, quad = lane >> 4;
    int rbase = bid * BM + wv * 32;

    f32x4 acc[2][8];
#pragma unroll
    for (int rt = 0; rt < 2; ++rt)
#pragma unroll
        for (int nt = 0; nt < 8; ++nt) acc[rt][nt] = (f32x4){0.f, 0.f, 0.f, 0.f};

#pragma unroll
    for (int kb = 0; kb < 4; ++kb) {
        bf16x8 af[2];
#pragma unroll
        for (int rt = 0; rt < 2; ++rt) {
            int row = rbase + rt * 16 + l16;
            if (row > nrows - 1) row = nrows - 1;
            if constexpr (BF16_IN) {
                const unsigned int* Xb = (const unsigned int*)Xv;
                af[rt] = *(const bf16x8*)&Xb[(size_t)row * 64 + kb * 16 + quad * 4];
            } else {
                const float* X = (const float*)Xv;
                float4 fa = ((const float4*)X)[(size_t)row * 32 + kb * 8 + quad * 2];
                float4 fb = ((const float4*)X)[(size_t)row * 32 + kb * 8 + quad * 2 + 1];
                union { uint4 u; bf16x8 v; } cv;
                cv.u.x = bf16pack(fa.x, fa.y);
                cv.u.y = bf16pack(fa.z, fa.w);
                cv.u.z = bf16pack(fb.x, fb.y);
                cv.u.w = bf16pack(fb.z, fb.w);
                af[rt] = cv.v;
            }
        }
        bf16x8 bfr[8];
#pragma unroll
        for (int nt = 0; nt < 8; ++nt) {
            int n = nt * 16 + l16;
            bfr[nt] = *(const bf16x8*)&Ws[n * 128 + (((kb * 4 + quad) ^ l16) << 3)];
        }
#pragma unroll
        for (int rt = 0; rt < 2; ++rt)
#pragma unroll
            for (int nt = 0; nt < 8; ++nt)
                acc[rt][nt] = __builtin_amdgcn_mfma_f32_16x16x32_bf16(
                    af[rt], bfr[nt], acc[rt][nt], 0, 0, 0);
    }

    short* Ys = (short*)Y;
#pragma unroll
    for (int rt = 0; rt < 2; ++rt)
#pragma unroll
        for (int reg = 0; reg < 4; ++reg) {
            int row = rbase + rt * 16 + quad * 4 + reg;
            if (row < nrows) {
#pragma unroll
                for (int nt = 0; nt < 8; ++nt)
                    Ys[(size_t)row * 128 + nt * 16 + l16] = (short)f2bf(acc[rt][nt][reg]);
            }
        }
}

// standalone GEMM (layer 2, bf16 input)
__global__ __launch_bounds__(256) void gemm128_mfma_bf16(const unsigned int* __restrict__ Xb,
                                                         const unsigned short* __restrict__ Wt,
                                                         unsigned int* __restrict__ Y,
                                                         int nrows) {
    __shared__ __align__(16) short Ws[128 * 128];
    gemm_body<true>(Xb, Wt, Y, nrows, blockIdx.x, Ws);
}

// ---------------- fused: gemm1 (f32 input) || pass2 fine sort --------------
// pass2 block k sorts bucket k: LDS fine hist (128 bins, LDS atomics), LDS
// scan -> row_ptr/dinv, scatter packed src ints into contiguous region.
// Independent of gemm1 -> one launch. pass2's ~11.5 KB lives inside Ws.
#define G_GEMM 782  // ceil(100000/128)
__global__ __launch_bounds__(256) void fused_gemm1_pass2(
    const float* __restrict__ feat, const unsigned short* __restrict__ wt1,
    unsigned int* __restrict__ Hb, const int* __restrict__ gcur,
    const unsigned int* __restrict__ temp, int* __restrict__ row_ptr,
    float* __restrict__ dinv, int* __restrict__ packed) {
    __shared__ __align__(16) short Ws[128 * 128];  // gemm tile / pass2 union
    int b = blockIdx.x, t = threadIdx.x;
    if (b < G_GEMM) {
        gemm_body<false>(feat, wt1, Hb, N_NODES, b, Ws);
        return;
    }
    int k = b - G_GEMM;
    unsigned int* ed = (unsigned int*)Ws;  // BCAP uints (8 KB)
    int* hist = (int*)(ed + BCAP);         // 128
    int* rp = hist + 128;                  // 128
    int* cur = rp + 128;                   // 128
    int* sc = cur + 128;                   // 128
    int* red = sc + 128;                   // 256

    // gbase = sum of gcur[j] for j<k (gcur tiny, L2-hot)
    int part = 0;
    for (int j = t; j < NB; j += 256)
        if (j < k) part += gcur[j];
    red[t] = part;
    __syncthreads();
    for (int off = 128; off > 0; off >>= 1) {
        if (t < off) red[t] += red[t + off];
        __syncthreads();
    }
    int gbase = red[0];
    int nk = gcur[k];
    if (nk > BCAP) nk = BCAP;

    if (t < 128) { hist[t] = 0; cur[t] = 0; }
    __syncthreads();
    for (int i = t; i < nk; i += 256) {
        unsigned int v = temp[(size_t)k * BCAP + i];
        ed[i] = v;
        atomicAdd(&hist[v >> 17], 1);
    }
    __syncthreads();

    // exclusive scan over 128 bins
    if (t < 128) sc[t] = hist[t];
    __syncthreads();
    for (int off = 1; off < 128; off <<= 1) {
        int a = (t < 128 && t >= off) ? sc[t - off] : 0;
        __syncthreads();
        if (t < 128) sc[t] += a;
        __syncthreads();
    }
    if (t < 128) {
        rp[t] = sc[t] - hist[t];
        int n = k * 128 + t;
        if (n < N_NODES) {
            row_ptr[n] = gbase + rp[t];
            dinv[n] = rsqrtf((float)(hist[t] + 1));  // +1 self-loop
        }
    }
    if (k == NB - 1 && t == 0) row_ptr[N_NODES] = N_EDGES;
    __syncthreads();

    for (int i = t; i < nk; i += 256) {
        unsigned int v = ed[i];
        int dl = v >> 17;
        int r = atomicAdd(&cur[dl], 1);
        packed[gbase + rp[dl] + r] = (int)(v & 0x1FFFF);
    }
}

// ---------------- gather-aggregate: 2 nodes/wave, 16 gathers in flight ----
// packed = src only (4B/edge). Meta lanes also fetch dinv[src] (L2-hot 400KB).
// x[v] = dv*(sum_s dinv[s]*H[s] + dv*H[v]) + bias; bias always added (b2
// folded here for layer 2 -> score is a pure dot).
template <bool RELU>
__global__ __launch_bounds__(256) void aggregate(const unsigned int* __restrict__ Hb,
                                                 const int* __restrict__ packed,
                                                 const int* __restrict__ row_ptr,
                                                 const float* __restrict__ dinv,
                                                 const float* __restrict__ bias,
                                                 unsigned int* __restrict__ Xb) {
    int v0 = blockIdx.x * 8 + (threadIdx.x >> 6) * 2;
    int v1 = v0 + 1;
    int lane = threadIdx.x & 63;
    if (v0 >= N_NODES) return;
    bool h1 = (v1 < N_NODES);

    int st0 = row_ptr[v0], en0 = row_ptr[v0 + 1];
    int st1 = h1 ? row_ptr[v1] : 0, en1 = h1 ? row_ptr[v1 + 1] : 0;
    float dv0 = dinv[v0];
    float dv1 = h1 ? dinv[v1] : 0.f;

    // A = dv*H[v] + sum_s dinv[s]*H[s]; x = dv*A
    unsigned int su0 = Hb[(size_t)v0 * 64 + lane];
    float a0 = dv0 * bflo(su0), a1 = dv0 * bfhi(su0);
    unsigned int su1 = h1 ? Hb[(size_t)v1 * 64 + lane] : 0u;
    float b0 = dv1 * bflo(su1), b1 = dv1 * bfhi(su1);

    for (int c0 = st0, c1 = st1; c0 < en0 || c1 < en1; c0 += 32, c1 += 32) {
        int n0 = en0 - c0; n0 = n0 < 0 ? 0 : (n0 > 32 ? 32 : n0);
        int n1 = en1 - c1; n1 = n1 < 0 ? 0 : (n1 > 32 ? 32 : n1);
        int p = 0;
        float d = 0.f;
        if (lane < 32) {
            if (lane < n0) { p = packed[c0 + lane]; d = dinv[p]; }
        } else {
            if (lane - 32 < n1) { p = packed[c1 + lane - 32]; d = dinv[p]; }
        }
        int nmax = n0 > n1 ? n0 : n1;
        for (int j = 0; j < nmax; j += 8) {
            int sA[8], sB[8];
            float dA[8], dB[8];
#pragma unroll
            for (int q = 0; q < 8; ++q) {
                sA[q] = __shfl(p, j + q);
                dA[q] = __shfl(d, j + q);
                sB[q] = __shfl(p, 32 + j + q);
                dB[q] = __shfl(d, 32 + j + q);
            }
            unsigned int uA[8], uB[8];
#pragma unroll
            for (int q = 0; q < 8; ++q) {
                uA[q] = Hb[(size_t)sA[q] * 64 + lane];
                uB[q] = Hb[(size_t)sB[q] * 64 + lane];
            }
#pragma unroll
            for (int q = 0; q < 8; ++q) {
                a0 = fmaf(dA[q], bflo(uA[q]), a0);
                a1 = fmaf(dA[q], bfhi(uA[q]), a1);
                b0 = fmaf(dB[q], bflo(uB[q]), b0);
                b1 = fmaf(dB[q], bfhi(uB[q]), b1);
            }
        }
    }

    float2 bb = ((const float2*)bias)[lane];
    a0 = fmaf(a0, dv0, bb.x);
    a1 = fmaf(a1, dv0, bb.y);
    b0 = fmaf(b0, dv1, bb.x);
    b1 = fmaf(b1, dv1, bb.y);
    if (RELU) {
        a0 = fmaxf(a0, 0.f);
        a1 = fmaxf(a1, 0.f);
        b0 = fmaxf(b0, 0.f);
        b1 = fmaxf(b1, 0.f);
    }
    Xb[(size_t)v0 * 64 + lane] = bf16pack(a0, a1);
    if (h1) Xb[(size_t)v1 * 64 + lane] = bf16pack(b0, b1);
}

// ---------------- edge scoring: 4 label edges per wave (bias pre-folded) ----
__global__ __launch_bounds__(256) void score_kernel(const int* __restrict__ ea,
                                                    const int* __restrict__ eb,
                                                    const unsigned int* __restrict__ Xb,
                                                    float* __restrict__ out) {
    int wbase = (blockIdx.x * 4 + (threadIdx.x >> 6)) * 4;
    int lane = threadIdx.x & 63;
    if (wbase >= N_LABEL) return;
    int ne = N_LABEL - wbase;
    if (ne > 4) ne = 4;

    unsigned int ua[4], ub[4];
#pragma unroll
    for (int e = 0; e < 4; ++e)
        if (e < ne) {
            int ia = ea[wbase + e], ib = eb[wbase + e];
            ua[e] = Xb[(size_t)ia * 64 + lane];
            ub[e] = Xb[(size_t)ib * 64 + lane];
        }
#pragma unroll
    for (int e = 0; e < 4; ++e)
        if (e < ne) {
            float p = bflo(ua[e]) * bflo(ub[e]) + bfhi(ua[e]) * bfhi(ub[e]);
#pragma unroll
            for (int off = 32; off > 0; off >>= 1) p += __shfl_down(p, off);
            if (lane == 0) out[wbase + e] = p;
        }
}

extern "C" void kernel_launch(void* const* d_in, const int* in_sizes, int n_in,
                              void* d_out, int out_size, void* d_ws, size_t ws_size,
                              hipStream_t stream) {
    const float* feat = (const float*)d_in[0];
    const int* ei = (const int*)d_in[1];
    const int* eli = (const int*)d_in[2];
    const float* W1 = (const float*)d_in[3];
    const float* b1 = (const float*)d_in[4];
    const float* W2 = (const float*)d_in[5];
    const float* b2 = (const float*)d_in[6];
    float* out = (float*)d_out;

    const int* src = ei;
    const int* dst = ei + N_EDGES;
    const int* la = eli;
    const int* lb = eli + N_LABEL;

    int* gcur = (int*)d_ws;                                   // NB (pad 1024)
    int* row_ptr = gcur + 1024;                               // N+4 ints
    float* dinv = (float*)(row_ptr + N_NODES + 4);            // N
    unsigned short* wt1 = (unsigned short*)(dinv + N_NODES);  // 16384 ushort
    unsigned short* wt2 = wt1 + 16384;                        // 16384 ushort
    int* packed = (int*)(wt2 + 16384);                        // E ints (4 MB)
    unsigned int* Hb = (unsigned int*)(packed + N_EDGES);     // N*64 uints
    unsigned int* Xb = Hb + (size_t)N_NODES * 64;             // N*64 uints
    unsigned int* temp = Xb;  // pass1/2 temp (6.4 MB) aliases Xb (dead til agg1)

    const int TB = 256;
    int gGemm = (N_NODES + BM - 1) / BM;  // 782
    int gAgg = (N_NODES + 7) / 8;         // 12500
    int gScore = (N_LABEL + 15) / 16;     // 12500

    hipMemsetAsync(gcur, 0, NB * sizeof(int), stream);

    // CSR coarse bucket (+ W conversion folded in)
    pass1_bucket_w2bf<<<P1_BLOCKS + 128, TB, 0, stream>>>(src, dst, gcur, temp,
                                                          W1, W2, wt1, wt2);

    // gemm1 || pass2 fine sort (independent)
    fused_gemm1_pass2<<<G_GEMM + NB, TB, 0, stream>>>(feat, wt1, Hb, gcur, temp,
                                                      row_ptr, dinv, packed);

    // layer 1 aggregate
    aggregate<true><<<gAgg, TB, 0, stream>>>(Hb, packed, row_ptr, dinv, b1, Xb);

    // layer 2
    gemm128_mfma_bf16<<<gGemm, TB, 0, stream>>>(Xb, wt2, Hb, N_NODES);
    aggregate<false><<<gAgg, TB, 0, stream>>>(Hb, packed, row_ptr, dinv, b2, Xb);

    // scoring (b2 already folded into Xb)
    score_kernel<<<gScore, TB, 0, stream>>>(la, lb, Xb, out);
}